// Round 2
// baseline (963.212 us; speedup 1.0000x reference)
//
#include <hip/hip_runtime.h>
#include <hip/hip_bf16.h>

// Problem constants (fixed by the reference)
#define D_DIM   512
#define N_NODES 65536
#define M_MUT   32768

typedef __bf16 bf16x8 __attribute__((ext_vector_type(8)));
typedef float  f32x4  __attribute__((ext_vector_type(4)));

// round-to-nearest-even fp32 -> bf16
__device__ __forceinline__ unsigned short f2bf_rn(float f) {
    unsigned int u = __float_as_uint(f);
    u += 0x7FFFu + ((u >> 16) & 1u);
    return (unsigned short)(u >> 16);
}

// fast tanh: 1 - 2/(1+exp(2x)); saturates correctly at +-inf of exp
__device__ __forceinline__ float fast_tanh(float x) {
    float e = __expf(2.0f * x);
    return 1.0f - 2.0f / (1.0f + e);
}

// async global->LDS, 16 bytes per lane (LDS dest wave-uniform base; HW adds lane*16)
__device__ __forceinline__ void async_ld16(void* lds, const void* g) {
    __builtin_amdgcn_global_load_lds(
        (__attribute__((address_space(1))) void*)(void*)g,
        (__attribute__((address_space(3))) void*)lds,
        16, 0, 0);
}

// ---------------------------------------------------------------------------
// prep: cast/transpose params to bf16 + init inverse maps to -1
// ---------------------------------------------------------------------------
__global__ void prep_kernel(const float* __restrict__ wo,
                            const float* __restrict__ wc,
                            const float* __restrict__ lw,
                            unsigned short* __restrict__ bto,
                            unsigned short* __restrict__ btc,
                            unsigned short* __restrict__ blw,
                            int* __restrict__ invp,
                            int* __restrict__ invk)
{
    int t = blockIdx.x * 256 + threadIdx.x;   // 1,179,648 threads
    if (t < 262144) {
        int n = t >> 9, k = t & 511;
        bto[t] = f2bf_rn(wo[k * 512 + n]);
    } else if (t < 524288) {
        int u = t - 262144;
        int n = u >> 9, k = u & 511;
        btc[u] = f2bf_rn(wc[k * 512 + n]);
    } else if (t < 1048576) {
        int u = t - 524288;
        blw[u] = f2bf_rn(lw[u]);
    } else {
        int u = t - 1048576;
        if (u < 65536) invp[u] = -1;
        else           invk[u - 65536] = -1;
    }
}

__global__ void scatter_inv_kernel(const int* __restrict__ idxp,
                                   const int* __restrict__ idxk,
                                   int* __restrict__ invp,
                                   int* __restrict__ invk)
{
    int m = blockIdx.x * 256 + threadIdx.x;   // M threads
    invp[idxp[m]] = m;
    invk[idxk[m]] = m;
}

// ---------------------------------------------------------------------------
// trans GEMM, fused epilogue:
//   acc[m,n] = (h @ W)[m,n]
//   if row mutual: g[inv(m), half*512 + n] = bf16(tanh(acc))   (consumed by gemm_out)
//   else:          out[m, n] = acc                              (final, nontemporal)
// 128x128 tile, BK=32, 256 threads (4 waves, 2x2 of 64x64).
// ---------------------------------------------------------------------------
__global__ __launch_bounds__(256)
void gemm_trans_kernel(const float* __restrict__ hp,
                       const float* __restrict__ hk,
                       const unsigned short* __restrict__ bto,
                       const unsigned short* __restrict__ btc,
                       const int* __restrict__ invp,
                       const int* __restrict__ invk,
                       unsigned short* __restrict__ g,
                       float* __restrict__ out)
{
    // swizzled grid: bands of 16 m-tiles x 4 n-tiles for L3 reuse of A
    const int bid  = blockIdx.x;           // 4096
    const int band = bid >> 6;
    const int rr_  = bid & 63;
    const int n0   = (rr_ & 3) * 128;
    const int m0   = (band * 16 + (rr_ >> 2)) * 128;

    const bool isP = (m0 < N_NODES);
    const int  mrel = isP ? m0 : m0 - N_NODES;
    const float* A = (isP ? hp : hk) + (size_t)mrel * D_DIM;
    const unsigned short* Bt = isP ? bto : btc;
    const int* inv = isP ? invp : invk;
    const int  gcol0 = isP ? 0 : 512;
    const size_t outbase = isP ? 0 : (size_t)N_NODES * D_DIM;

    __shared__ __align__(16) unsigned short smem[128 * 32 * 2];  // 16 KB
    unsigned short* As = smem;
    unsigned short* Bs = smem + 128 * 32;

    const int tid  = threadIdx.x;
    const int lane = tid & 63;
    const int wid  = tid >> 6;
    const int wm   = (wid & 1) * 64;
    const int wn   = (wid >> 1) * 64;
    const int r16  = lane & 15;
    const int q    = lane >> 4;

    f32x4 acc[4][4] = {};

    const int ag_row = tid >> 2;           // 0..63 (+64 for i=1)
    const int ag_c8  = (tid & 3) * 8;      // 0,8,16,24

    for (int kk = 0; kk < 16; ++kk) {
        const int k0 = kk * 32;
        // stage A: fp32 -> bf16 via VGPR round-trip
        #pragma unroll
        for (int i = 0; i < 2; ++i) {
            const int row = ag_row + i * 64;
            const float* src = A + (size_t)row * D_DIM + k0 + ag_c8;
            float4 v0 = *(const float4*)src;
            float4 v1 = *(const float4*)(src + 4);
            uint4 u;
            u.x = f2bf_rn(v0.x) | ((unsigned)f2bf_rn(v0.y) << 16);
            u.y = f2bf_rn(v0.z) | ((unsigned)f2bf_rn(v0.w) << 16);
            u.z = f2bf_rn(v1.x) | ((unsigned)f2bf_rn(v1.y) << 16);
            u.w = f2bf_rn(v1.z) | ((unsigned)f2bf_rn(v1.w) << 16);
            *(uint4*)&As[(row * 4 + (tid & 3)) * 8] = u;
        }
        // stage B: async 16B/lane
        #pragma unroll
        for (int i = 0; i < 2; ++i) {
            const int c  = i * 256 + wid * 64 + lane;
            const int bn = c >> 2, k8 = (c & 3) * 8;
            async_ld16(&Bs[(i * 256 + wid * 64) * 8],
                       Bt + (size_t)(n0 + bn) * D_DIM + k0 + k8);
        }
        __syncthreads();
        bf16x8 af[4], bfr[4];
        #pragma unroll
        for (int mi = 0; mi < 4; ++mi)
            af[mi] = *(const bf16x8*)&As[(wm + mi * 16 + r16) * 32 + q * 8];
        #pragma unroll
        for (int ni = 0; ni < 4; ++ni)
            bfr[ni] = *(const bf16x8*)&Bs[(wn + ni * 16 + r16) * 32 + q * 8];
        #pragma unroll
        for (int mi = 0; mi < 4; ++mi)
            #pragma unroll
            for (int ni = 0; ni < 4; ++ni)
                acc[mi][ni] = __builtin_amdgcn_mfma_f32_16x16x32_bf16(
                    af[mi], bfr[ni], acc[mi][ni], 0, 0, 0);
        __syncthreads();
    }

    // ---- epilogue via per-wave LDS transpose (4 KB/wave) ----
    float* epi = (float*)smem + wid * 1024;
    const int erow = lane >> 2;          // 0..15
    const int ec0  = (lane & 3) * 16;    // 0,16,32,48

    #pragma unroll
    for (int mi = 0; mi < 4; ++mi) {
        #pragma unroll
        for (int ni = 0; ni < 4; ++ni)
            #pragma unroll
            for (int r2 = 0; r2 < 4; ++r2)
                epi[(q * 4 + r2) * 64 + ni * 16 + r16] = acc[mi][ni][r2];
        __syncthreads();

        const int lrow = mrel + wm + mi * 16 + erow;   // row within this half
        const int iv   = inv[lrow];
        f32x4 vv[4];
        #pragma unroll
        for (int c = 0; c < 4; ++c)
            vv[c] = *(const f32x4*)&epi[erow * 64 + ec0 + c * 4];

        if (iv >= 0) {
            // mutual row -> g as bf16(tanh(v)), 32B contiguous per lane
            unsigned int hh[8];
            #pragma unroll
            for (int c = 0; c < 4; ++c) {
                unsigned short a0 = f2bf_rn(fast_tanh(vv[c][0]));
                unsigned short a1 = f2bf_rn(fast_tanh(vv[c][1]));
                unsigned short a2 = f2bf_rn(fast_tanh(vv[c][2]));
                unsigned short a3 = f2bf_rn(fast_tanh(vv[c][3]));
                hh[c * 2]     = (unsigned)a0 | ((unsigned)a1 << 16);
                hh[c * 2 + 1] = (unsigned)a2 | ((unsigned)a3 << 16);
            }
            unsigned short* gp = g + (size_t)iv * 1024 + gcol0 + n0 + wn + ec0;
            uint4 u0 = {hh[0], hh[1], hh[2], hh[3]};
            uint4 u1 = {hh[4], hh[5], hh[6], hh[7]};
            *(uint4*)gp       = u0;
            *((uint4*)gp + 1) = u1;
        } else {
            // non-mutual row -> final out, nontemporal 64B per lane
            float* op = out + outbase + (size_t)lrow * D_DIM + n0 + wn + ec0;
            #pragma unroll
            for (int c = 0; c < 4; ++c)
                __builtin_nontemporal_store(vv[c], (f32x4*)op + c);
        }
        __syncthreads();
    }
}

// ---------------------------------------------------------------------------
// out GEMM + epilogue + dual scatter:
//   v = leaky_relu(g @ lin_w^T + lin_b, 0.01) + bias
//   out[idxp[m]] = v ; out[half + idxk[m]] = v
// ---------------------------------------------------------------------------
__global__ __launch_bounds__(256)
void gemm_out_kernel(const unsigned short* __restrict__ g,
                     const unsigned short* __restrict__ blw,
                     const float* __restrict__ lin_b,
                     const float* __restrict__ bias,
                     const int* __restrict__ idxp,
                     const int* __restrict__ idxk,
                     float* __restrict__ out)
{
    const int bid  = blockIdx.x;          // 1024
    const int band = bid >> 6;
    const int rr_  = bid & 63;
    const int n0   = (rr_ & 3) * 128;
    const int m0   = (band * 16 + (rr_ >> 2)) * 128;

    __shared__ __align__(16) unsigned short smem[128 * 32 * 2];  // 16 KB
    unsigned short* As = smem;
    unsigned short* Bs = smem + 128 * 32;

    const int tid  = threadIdx.x;
    const int lane = tid & 63;
    const int wid  = tid >> 6;
    const int wm   = (wid & 1) * 64;
    const int wn   = (wid >> 1) * 64;
    const int r16  = lane & 15;
    const int q    = lane >> 4;

    f32x4 acc[4][4] = {};

    for (int kk = 0; kk < 32; ++kk) {     // K = 1024
        const int k0 = kk * 32;
        #pragma unroll
        for (int i = 0; i < 2; ++i) {
            const int c = i * 256 + wid * 64 + lane;
            const int ar = c >> 2, k8 = (c & 3) * 8;
            async_ld16(&As[(i * 256 + wid * 64) * 8],
                       g + (size_t)(m0 + ar) * 1024 + k0 + k8);
        }
        #pragma unroll
        for (int i = 0; i < 2; ++i) {
            const int c = i * 256 + wid * 64 + lane;
            const int bn = c >> 2, k8 = (c & 3) * 8;
            async_ld16(&Bs[(i * 256 + wid * 64) * 8],
                       blw + (size_t)(n0 + bn) * 1024 + k0 + k8);
        }
        __syncthreads();
        bf16x8 af[4], bfr[4];
        #pragma unroll
        for (int mi = 0; mi < 4; ++mi)
            af[mi] = *(const bf16x8*)&As[(wm + mi * 16 + r16) * 32 + q * 8];
        #pragma unroll
        for (int ni = 0; ni < 4; ++ni)
            bfr[ni] = *(const bf16x8*)&Bs[(wn + ni * 16 + r16) * 32 + q * 8];
        #pragma unroll
        for (int mi = 0; mi < 4; ++mi)
            #pragma unroll
            for (int ni = 0; ni < 4; ++ni)
                acc[mi][ni] = __builtin_amdgcn_mfma_f32_16x16x32_bf16(
                    af[mi], bfr[ni], acc[mi][ni], 0, 0, 0);
        __syncthreads();
    }

    // ---- epilogue via per-wave LDS transpose ----
    float* epi = (float*)smem + wid * 1024;
    const int erow = lane >> 2;
    const int ec0  = (lane & 3) * 16;
    const int col0 = n0 + wn + ec0;

    f32x4 lb[4], bs[4];
    #pragma unroll
    for (int c = 0; c < 4; ++c) {
        lb[c] = *(const f32x4*)(lin_b + col0 + c * 4);
        bs[c] = *(const f32x4*)(bias  + col0 + c * 4);
    }
    const size_t half = (size_t)N_NODES * D_DIM;

    #pragma unroll
    for (int mi = 0; mi < 4; ++mi) {
        #pragma unroll
        for (int ni = 0; ni < 4; ++ni)
            #pragma unroll
            for (int r2 = 0; r2 < 4; ++r2)
                epi[(q * 4 + r2) * 64 + ni * 16 + r16] = acc[mi][ni][r2];
        __syncthreads();

        const int m  = m0 + wm + mi * 16 + erow;
        const int dp = idxp[m];
        const int dk = idxk[m];
        f32x4 vv[4];
        #pragma unroll
        for (int c = 0; c < 4; ++c) {
            f32x4 v = *(const f32x4*)&epi[erow * 64 + ec0 + c * 4];
            #pragma unroll
            for (int e = 0; e < 4; ++e) {
                float x = v[e] + lb[c][e];
                x = x > 0.0f ? x : 0.01f * x;
                v[e] = x + bs[c][e];
            }
            vv[c] = v;
        }
        float* p1 = out + (size_t)dp * D_DIM + col0;
        float* p2 = out + half + (size_t)dk * D_DIM + col0;
        #pragma unroll
        for (int c = 0; c < 4; ++c) {
            __builtin_nontemporal_store(vv[c], (f32x4*)p1 + c);
            __builtin_nontemporal_store(vv[c], (f32x4*)p2 + c);
        }
        __syncthreads();
    }
}

// ---------------------------------------------------------------------------
extern "C" void kernel_launch(void* const* d_in, const int* in_sizes, int n_in,
                              void* d_out, int out_size, void* d_ws, size_t ws_size,
                              hipStream_t stream)
{
    const float* h_p  = (const float*)d_in[0];
    const float* h_k  = (const float*)d_in[1];
    const int*   idxp = (const int*)d_in[2];
    const int*   idxk = (const int*)d_in[3];
    // d_in[4] = last_x (unused by the reference computation)
    const float* w_o  = (const float*)d_in[5];
    const float* w_c  = (const float*)d_in[6];
    const float* linw = (const float*)d_in[7];
    const float* linb = (const float*)d_in[8];
    const float* bias = (const float*)d_in[9];
    float* out = (float*)d_out;

    // ws layout (bf16 as ushort): g[32768*1024] | bto | btc | blw | invp | invk
    unsigned short* g   = (unsigned short*)d_ws;
    unsigned short* bto = g + (size_t)M_MUT * 1024;
    unsigned short* btc = bto + 512 * 512;
    unsigned short* blw = btc + 512 * 512;
    int* invp = (int*)(blw + 512 * 1024);
    int* invk = invp + N_NODES;
    // total ws ~ 66.5 MB

    prep_kernel<<<4608, 256, 0, stream>>>(w_o, w_c, linw, bto, btc, blw, invp, invk);
    scatter_inv_kernel<<<M_MUT / 256, 256, 0, stream>>>(idxp, idxk, invp, invk);
    gemm_trans_kernel<<<4096, 256, 0, stream>>>(h_p, h_k, bto, btc, invp, invk, g, out);
    gemm_out_kernel<<<1024, 256, 0, stream>>>(g, blw, linb, bias, idxp, idxk, out);
}